// Round 6
// baseline (539.338 us; speedup 1.0000x reference)
//
#include <hip/hip_runtime.h>

// VectorQuantiser forward, MI355X fp32.
// N=65536 tokens (16x64x64, channel dim 64 strided by 4096), K=1024 codes, D=64.
//
// Round 8: scores via MFMA phase-1 + margin shortlist + EXACT fp32 rescore.
// Rounds 2-7 proved both fp32 structures are capped (~165-190us): thread=token
// is allocator-defeated (VGPR pinned at 52 through pins+clobber at cap 128),
// LDS-GEMM is LDS-pipe bound. New engine: 3-pass bf16-split MFMA computes
// s~ with |s~ - d| <= ~4e-5 (split residual 2^-16-scale + fp32-accum + 1 ulp
// at |d|<=139); any 128-code block / 128-token group within MARGIN=2e-4 of
// the max is rescored with the BIT-IDENTICAL 4-chain fp32 formula (stored
// zn2/en2, same fmaf chains, same key packing). The true argmax is provably
// inside the shortlist, so wsrow/wscol — and every output — are bit-identical
// to the thrice-passing round-2 code. A/B fragment k-permutations cancel
// (same slot->channel map both operands); only the m89-verified C/D layout
// (col=lane&15, row=(lane>>4)*4+j) is load-bearing.
// Scratch: z bf16 hi/lo = 16.77MB = exactly out_zq (dead before k_tokens
// overwrites it); candidate lists overlay it after k_mfma. ws grows to 5.3MB
// (rowbm 2MB, colbm 2MB, zn2 256KB, ebf 256KB).

#define MARGIN 2e-4f

// ---- ws layout (bytes) ----
#define WS_ROW   0         // u64 wsrow[65536]
#define WS_COL   524288    // u64 wscol[1024]
#define WS_CNT   532480    // u32 counts[1024]
#define WS_LOSS  536576    // double loss_acc
#define WS_EN2   536592    // float en2[1024]
#define WS_LCNT  540688    // u32 lcnt[8]
#define WS_ZN2   541696    // float zn2[65536]            (256KB)
#define WS_EBH   803840    // u16 ebf_hi[1024*64]         (128KB)
#define WS_EBL   934912    // u16 ebf_lo[1024*64]         (128KB)
#define WS_RBM   1065984   // f32 rowbm[65536][8]         (2MB)
#define WS_CBM   3163136   // f32 colbm[1024][512]        (2MB)
#define WS_BYTES 5260288
#define WS_ZERO  540720    // memset range: row/col/cnt/loss/lcnt

typedef __attribute__((ext_vector_type(8))) short short8v;
typedef __attribute__((ext_vector_type(4))) float f32x4;

__device__ __forceinline__ unsigned int f32_ord(float x) {
    unsigned int b = __float_as_uint(x);
    return (b & 0x80000000u) ? ~b : (b | 0x80000000u);
}

__device__ __forceinline__ unsigned short f2bf(float f) {  // RNE fp32->bf16
    unsigned int u = __float_as_uint(f);
    return (unsigned short)((u + 0x7FFFu + ((u >> 16) & 1u)) >> 16);
}
__device__ __forceinline__ float bf2f(unsigned short h) {
    return __uint_as_float((unsigned int)h << 16);
}

// numpy pairwise sum of squares over 64 values (verbatim from passing code).
template <typename F>
__device__ __forceinline__ float np_pairwise64_sq(F get) {
    float r[8];
#pragma unroll
    for (int j = 0; j < 8; ++j) {
        float v = get(j);
        r[j] = __fmul_rn(v, v);
    }
#pragma unroll
    for (int i = 8; i < 64; i += 8) {
#pragma unroll
        for (int j = 0; j < 8; ++j) {
            float v = get(i + j);
            r[j] = __fadd_rn(r[j], __fmul_rn(v, v));
        }
    }
    return __fadd_rn(__fadd_rn(__fadd_rn(r[0], r[1]), __fadd_rn(r[2], r[3])),
                     __fadd_rn(__fadd_rn(r[4], r[5]), __fadd_rn(r[6], r[7])));
}

// ---- K0: norms + bf16 hi/lo splits ----
__global__ __launch_bounds__(256) void k_prep(
    const float* __restrict__ z, const float* __restrict__ emb,
    float* __restrict__ en2, float* __restrict__ zn2,
    unsigned int* __restrict__ zbh32, unsigned int* __restrict__ zbl32,
    unsigned int* __restrict__ ebh32, unsigned int* __restrict__ ebl32) {
    if (blockIdx.x < 4) {
        const int k = blockIdx.x * 256 + threadIdx.x;
        const float* a = emb + (size_t)k * 64;
        float ar[64];
#pragma unroll
        for (int i = 0; i < 64; ++i) ar[i] = a[i];
        en2[k] = np_pairwise64_sq([&](int i) { return ar[i]; });
#pragma unroll
        for (int wd = 0; wd < 32; ++wd) {
            float e0 = ar[2 * wd], e1 = ar[2 * wd + 1];
            unsigned short h0 = f2bf(e0), h1 = f2bf(e1);
            ebh32[k * 32 + wd] = (unsigned int)h0 | ((unsigned int)h1 << 16);
            unsigned short l0 = f2bf(__fsub_rn(e0, bf2f(h0)));
            unsigned short l1 = f2bf(__fsub_rn(e1, bf2f(h1)));
            ebl32[k * 32 + wd] = (unsigned int)l0 | ((unsigned int)l1 << 16);
        }
    } else {
        const int n = (blockIdx.x - 4) * 256 + threadIdx.x;
        const int b = n >> 12, hw = n & 4095;
        const float* zp = z + (size_t)b * 262144 + hw;
        float zr[64];
#pragma unroll
        for (int c = 0; c < 64; ++c) zr[c] = zp[(size_t)c * 4096];
        zn2[n] = np_pairwise64_sq([&](int i) { return zr[i]; });
#pragma unroll
        for (int wd = 0; wd < 32; ++wd) {
            float z0 = zr[2 * wd], z1 = zr[2 * wd + 1];
            unsigned short h0 = f2bf(z0), h1 = f2bf(z1);
            zbh32[n * 32 + wd] = (unsigned int)h0 | ((unsigned int)h1 << 16);
            unsigned short l0 = f2bf(__fsub_rn(z0, bf2f(h0)));
            unsigned short l1 = f2bf(__fsub_rn(z1, bf2f(h1)));
            zbl32[n * 32 + wd] = (unsigned int)l0 | ((unsigned int)l1 << 16);
        }
    }
}

// ---- K1: approximate scores via 3-pass bf16 MFMA + block maxes ----
// grid 512 blocks x 512 thr (8 waves). Wave w: tokens tw..tw+15, all 1024
// codes in 64 chunks of 16. s~ = fadd(fsub(-zn2, en2), 2*mfma_dot).
__global__ __launch_bounds__(512) void k_mfma(
    const unsigned short* __restrict__ zbh, const unsigned short* __restrict__ zbl,
    const unsigned short* __restrict__ ebh, const unsigned short* __restrict__ ebl,
    const float* __restrict__ zn2, const float* __restrict__ en2,
    float* __restrict__ rbm, float* __restrict__ cbm) {
    const int t = threadIdx.x, l = t & 63, w = t >> 6;
    const int n0 = blockIdx.x * 128;
    const int tw = n0 + w * 16;
    const int lm = l & 15, kg = l >> 4;

    __shared__ float en2l[1024];
    __shared__ float colmax[8][1024];

    for (int i = t; i < 1024; i += 512) en2l[i] = en2[i];
    __syncthreads();

    const int tok = tw + lm;
    const short8v ah0 = *reinterpret_cast<const short8v*>(zbh + tok * 64 + kg * 8);
    const short8v ah1 = *reinterpret_cast<const short8v*>(zbh + tok * 64 + 32 + kg * 8);
    const short8v al0 = *reinterpret_cast<const short8v*>(zbl + tok * 64 + kg * 8);
    const short8v al1 = *reinterpret_cast<const short8v*>(zbl + tok * 64 + 32 + kg * 8);

    float nzn2[4];
    {
        const float4 zv = *reinterpret_cast<const float4*>(zn2 + tw + kg * 4);
        nzn2[0] = -zv.x; nzn2[1] = -zv.y; nzn2[2] = -zv.z; nzn2[3] = -zv.w;
    }

    float rmax[4] = {-3.4e38f, -3.4e38f, -3.4e38f, -3.4e38f};

    for (int c = 0; c < 64; ++c) {
        const int code = c * 16 + lm;
        const unsigned short* eh = ebh + code * 64 + kg * 8;
        const unsigned short* el = ebl + code * 64 + kg * 8;
        const short8v bh0 = *reinterpret_cast<const short8v*>(eh);
        const short8v bh1 = *reinterpret_cast<const short8v*>(eh + 32);
        const short8v bl0 = *reinterpret_cast<const short8v*>(el);
        const short8v bl1 = *reinterpret_cast<const short8v*>(el + 32);

        f32x4 acc = {0.f, 0.f, 0.f, 0.f};
        acc = __builtin_amdgcn_mfma_f32_16x16x32_bf16(ah0, bh0, acc, 0, 0, 0);
        acc = __builtin_amdgcn_mfma_f32_16x16x32_bf16(ah1, bh1, acc, 0, 0, 0);
        acc = __builtin_amdgcn_mfma_f32_16x16x32_bf16(ah0, bl0, acc, 0, 0, 0);
        acc = __builtin_amdgcn_mfma_f32_16x16x32_bf16(ah1, bl1, acc, 0, 0, 0);
        acc = __builtin_amdgcn_mfma_f32_16x16x32_bf16(al0, bh0, acc, 0, 0, 0);
        acc = __builtin_amdgcn_mfma_f32_16x16x32_bf16(al1, bh1, acc, 0, 0, 0);

        const float en2v = en2l[code];
        float cm = -3.4e38f;
#pragma unroll
        for (int j = 0; j < 4; ++j) {
            float s = __fadd_rn(__fsub_rn(nzn2[j], en2v), 2.0f * acc[j]);
            rmax[j] = fmaxf(rmax[j], s);
            cm = fmaxf(cm, s);
        }
        // column: combine the 4 row-quadrants -> wave's 16-token col max
        cm = fmaxf(cm, __shfl_xor(cm, 16, 64));
        cm = fmaxf(cm, __shfl_xor(cm, 32, 64));
        if (l < 16) colmax[w][c * 16 + l] = cm;

        if ((c & 7) == 7) {  // flush a 128-code block of row maxes
#pragma unroll
            for (int j = 0; j < 4; ++j) {
                float r = rmax[j];
                r = fmaxf(r, __shfl_xor(r, 1, 64));
                r = fmaxf(r, __shfl_xor(r, 2, 64));
                r = fmaxf(r, __shfl_xor(r, 4, 64));
                r = fmaxf(r, __shfl_xor(r, 8, 64));
                if (lm == 0)
                    rbm[(size_t)(tw + kg * 4 + j) * 8 + (c >> 3)] = r;
                rmax[j] = -3.4e38f;
            }
        }
    }
    __syncthreads();
    for (int code = t; code < 1024; code += 512) {
        float m = colmax[0][code];
#pragma unroll
        for (int q = 1; q < 8; ++q) m = fmaxf(m, colmax[q][code]);
        cbm[(size_t)code * 512 + blockIdx.x] = m;
    }
}

// ---- K2: per-token candidate lists from row block-maxes ----
__global__ __launch_bounds__(256) void k_rowmax(
    const float* __restrict__ rbm, unsigned int* __restrict__ lcnt,
    unsigned int* __restrict__ lists) {
    const int n = blockIdx.x * 256 + threadIdx.x;
    const float* bm = rbm + (size_t)n * 8;
    float v[8];
    float g = -3.4e38f;
#pragma unroll
    for (int i = 0; i < 8; ++i) { v[i] = bm[i]; g = fmaxf(g, v[i]); }
    const float thr = g - MARGIN;
#pragma unroll
    for (int cb = 0; cb < 8; ++cb) {
        if (v[cb] >= thr) {
            unsigned int pos = atomicAdd(&lcnt[cb], 1u);
            lists[cb * 65536 + pos] = (unsigned int)n;
        }
    }
}

// ---- K3: exact row rescore (bit-identical 4-chain d) over candidates ----
__global__ __launch_bounds__(256) void k_rowrescore(
    const float* __restrict__ z, const float* __restrict__ emb,
    const float* __restrict__ zn2, const float* __restrict__ en2,
    const unsigned int* __restrict__ lists, const unsigned int* __restrict__ lcnt,
    unsigned long long* __restrict__ wsrow) {
    const int cb = blockIdx.x;
    const unsigned int cnt = lcnt[cb];
    const unsigned int* list = lists + cb * 65536;
    const float4* E4 = reinterpret_cast<const float4*>(emb);
    for (unsigned int i = blockIdx.y * 256 + threadIdx.x; i < cnt; i += 16 * 256) {
        const int n = (int)list[i];
        const int b = n >> 12, hw = n & 4095;
        const float* zp = z + (size_t)b * 262144 + hw;
        const float nzn2 = -zn2[n];
        unsigned long long best = 0ull;
        for (int kk = 0; kk < 128; ++kk) {
            const int k = cb * 128 + kk;
            const float4* ek = E4 + (size_t)k * 16;  // wave-uniform -> s_load
            float c0 = 0.f, c1 = 0.f, c2 = 0.f, c3 = 0.f;
#pragma unroll
            for (int j = 0; j < 16; ++j) {
                float4 e = ek[j];
                c0 = fmaf(e.x, zp[(size_t)(4 * j + 0) * 4096], c0);
                c1 = fmaf(e.y, zp[(size_t)(4 * j + 1) * 4096], c1);
                c2 = fmaf(e.z, zp[(size_t)(4 * j + 2) * 4096], c2);
                c3 = fmaf(e.w, zp[(size_t)(4 * j + 3) * 4096], c3);
            }
            float dot = (c0 + c1) + (c2 + c3);
            float d = __fadd_rn(__fsub_rn(nzn2, en2[k]), 2.0f * dot);
            unsigned long long key =
                ((unsigned long long)f32_ord(d) << 32) |
                (unsigned long long)(unsigned int)(~(unsigned int)k);
            if (key > best) best = key;   // ties: larger key = smaller k
        }
        atomicMax(&wsrow[n], best);
    }
}

// ---- K4: exact column rescore over candidate token-groups ----
__global__ __launch_bounds__(256) void k_colrescore(
    const float* __restrict__ z, const float* __restrict__ emb,
    const float* __restrict__ zn2, const float* __restrict__ en2,
    const float* __restrict__ cbm, unsigned long long* __restrict__ wscol) {
    const int k = blockIdx.x, t = threadIdx.x;
    __shared__ float sbm[512];
    __shared__ float red[256];
    float a = cbm[(size_t)k * 512 + t];
    float b = cbm[(size_t)k * 512 + 256 + t];
    sbm[t] = a; sbm[t + 256] = b;
    red[t] = fmaxf(a, b);
    __syncthreads();
    for (int st = 128; st; st >>= 1) {
        if (t < st) red[t] = fmaxf(red[t], red[t + st]);
        __syncthreads();
    }
    const float thr = red[0] - MARGIN;
    const float en2k = en2[k];
    const float4* ek = reinterpret_cast<const float4*>(emb + (size_t)k * 64);

    for (int g = 0; g < 512; ++g) {
        if (sbm[g] >= thr) {     // uniform branch
            if (t < 128) {
                const int n = g * 128 + t;
                const int b2 = n >> 12, hw = n & 4095;
                const float* zp = z + (size_t)b2 * 262144 + hw;
                float c0 = 0.f, c1 = 0.f, c2 = 0.f, c3 = 0.f;
#pragma unroll
                for (int j = 0; j < 16; ++j) {
                    float4 e = ek[j];
                    c0 = fmaf(e.x, zp[(size_t)(4 * j + 0) * 4096], c0);
                    c1 = fmaf(e.y, zp[(size_t)(4 * j + 1) * 4096], c1);
                    c2 = fmaf(e.z, zp[(size_t)(4 * j + 2) * 4096], c2);
                    c3 = fmaf(e.w, zp[(size_t)(4 * j + 3) * 4096], c3);
                }
                float dot = (c0 + c1) + (c2 + c3);
                float d = __fadd_rn(__fsub_rn(-zn2[n], en2k), 2.0f * dot);
                unsigned long long key =
                    ((unsigned long long)f32_ord(d) << 32) |
                    (unsigned long long)(unsigned int)(~(unsigned int)n);
#pragma unroll
                for (int m = 1; m < 64; m <<= 1) {
                    unsigned long long o = __shfl_xor(key, m, 64);
                    if (o > key) key = o;    // ties: larger key = smaller n
                }
                if ((t & 63) == 0) atomicMax(&wscol[k], key);
            }
        }
    }
}

// ---- K5: per-token outputs: z_q (straight-through), indices, hist, loss ----
__global__ __launch_bounds__(256) void k_tokens(
    const float* __restrict__ z, const float* __restrict__ emb,
    const unsigned long long* __restrict__ wsrow,
    unsigned int* __restrict__ counts, double* __restrict__ loss_acc,
    float* __restrict__ out_zq, float* __restrict__ out_idx) {
    const int n  = blockIdx.x * 256 + threadIdx.x;
    const int b  = n >> 12;
    const int hw = n & 4095;

    unsigned long long key = wsrow[n];
    int idx = (int)(~(unsigned int)(key & 0xFFFFFFFFull));
    out_idx[n] = (float)idx;
    atomicAdd(&counts[idx], 1u);

    const float* zp = z + (size_t)b * 262144 + hw;
    float*       op = out_zq + (size_t)b * 262144 + hw;
    const float* ep = emb + (size_t)idx * 64;

    double ls = 0.0;
#pragma unroll
    for (int c = 0; c < 64; ++c) {
        float zc   = zp[(size_t)c * 4096];
        float eq   = ep[c];
        float diff = __fsub_rn(eq, zc);              // fl(z_q - zc)
        float sq   = __fmul_rn(diff, diff);
        ls += (double)sq;
        op[(size_t)c * 4096] = __fadd_rn(zc, diff);  // zc + fl(z_q - zc)
    }

    __shared__ double sred[256];
    sred[threadIdx.x] = ls;
    __syncthreads();
    for (int st = 128; st; st >>= 1) {
        if (threadIdx.x < st) sred[threadIdx.x] += sred[threadIdx.x + st];
        __syncthreads();
    }
    if (threadIdx.x == 0) atomicAdd(loss_acc, sred[0]);
}

// ---- K6: tail — new embedding (all blocks) + scalars (block 0 only) ----
__global__ __launch_bounds__(1024) void k_tail(
    const float* __restrict__ z, const float* __restrict__ emb,
    const float* __restrict__ embed_prob,
    const unsigned long long* __restrict__ wscol,
    const unsigned int* __restrict__ counts,
    const double* __restrict__ loss_acc,
    float* __restrict__ out_newemb, float* __restrict__ out_loss,
    float* __restrict__ out_perp, float* __restrict__ out_prob) {
    const int k = blockIdx.x * 16 + (threadIdx.x >> 6);
    const int c = threadIdx.x & 63;

    float avg  = (float)counts[k] * (1.0f / 65536.0f);
    float pnew = __fadd_rn(__fmul_rn(embed_prob[k], 0.99f),
                           __fmul_rn(0.01f, avg));
    float tt = __fdiv_rn(__fmul_rn(__fmul_rn(pnew, 1024.0f), 10.0f), 0.01f);
    float dk = expf(__fsub_rn(-tt, 1e-3f));
    float omd = __fsub_rn(1.0f, dk);

    unsigned long long ck = wscol[k];
    int cn  = (int)(~(unsigned int)(ck & 0xFFFFFFFFull));
    int cb  = cn >> 12;
    int chw = cn & 4095;

    float rf = z[(size_t)cb * 262144 + (size_t)c * 4096 + chw];
    float e  = emb[(size_t)k * 64 + c];
    out_newemb[(size_t)k * 64 + c] =
        __fadd_rn(__fmul_rn(e, omd), __fmul_rn(rf, dk));

    if (blockIdx.x == 0) {
        const int q = threadIdx.x;

        float avg2  = (float)counts[q] * (1.0f / 65536.0f);
        float pnew2 = __fadd_rn(__fmul_rn(embed_prob[q], 0.99f),
                                __fmul_rn(0.01f, avg2));
        out_prob[q] = pnew2;

        float term = __fmul_rn(avg2, logf(__fadd_rn(avg2, 1e-10f)));
        __shared__ double red[1024];
        red[q] = (double)term;
        __syncthreads();
        for (int st = 512; st; st >>= 1) {
            if (q < st) red[q] += red[q + st];
            __syncthreads();
        }
        if (q == 0) {
            float s32 = (float)red[0];
            out_perp[0] = expf(-s32);
            double lm = loss_acc[0] / 4194304.0;
            float  m  = (float)lm;
            out_loss[0] = __fadd_rn(__fmul_rn(0.25f, m), m);  // BETA*m + m
        }
    }
}

extern "C" void kernel_launch(void* const* d_in, const int* in_sizes, int n_in,
                              void* d_out, int out_size, void* d_ws, size_t ws_size,
                              hipStream_t stream) {
    const float* z    = (const float*)d_in[0];   // 16*64*64*64
    const float* emb  = (const float*)d_in[1];   // 1024*64
    const float* prob = (const float*)d_in[2];   // 1024

    float* out        = (float*)d_out;
    float* out_zq     = out;                 // 4194304 floats (16.777 MB)
    float* out_loss   = out + 4194304;
    float* out_perp   = out + 4194305;
    float* out_newemb = out + 4194306;
    float* out_prob   = out + 4259842;
    float* out_idx    = out + 4260866;

    char* ws = (char*)d_ws;
    unsigned long long* wsrow = (unsigned long long*)(ws + WS_ROW);
    unsigned long long* wscol = (unsigned long long*)(ws + WS_COL);
    unsigned int*       cnts  = (unsigned int*)(ws + WS_CNT);
    double*             lacc  = (double*)(ws + WS_LOSS);
    float*              en2   = (float*)(ws + WS_EN2);
    unsigned int*       lcnt  = (unsigned int*)(ws + WS_LCNT);
    float*              zn2   = (float*)(ws + WS_ZN2);
    unsigned short*     ebh   = (unsigned short*)(ws + WS_EBH);
    unsigned short*     ebl   = (unsigned short*)(ws + WS_EBL);
    float*              rbm   = (float*)(ws + WS_RBM);
    float*              cbm   = (float*)(ws + WS_CBM);

    // out_zq doubles as scratch before k_tokens rewrites it:
    //   zbf_hi u16[4.2M] @ bytes [0, 8388608)
    //   zbf_lo u16[4.2M] @ bytes [8388608, 16777216)
    //   lists  u32[8][65536] @ bytes [0, 2097152)   (after k_mfma is done)
    unsigned short* zbh  = (unsigned short*)out_zq;
    unsigned short* zbl  = (unsigned short*)((char*)out_zq + 8388608);
    unsigned int*  lists = (unsigned int*)out_zq;

    hipMemsetAsync(d_ws, 0, WS_ZERO, stream);

    hipLaunchKernelGGL(k_prep, dim3(260), dim3(256), 0, stream,
                       z, emb, en2, zn2,
                       (unsigned int*)zbh, (unsigned int*)zbl,
                       (unsigned int*)ebh, (unsigned int*)ebl);
    hipLaunchKernelGGL(k_mfma, dim3(512), dim3(512), 0, stream,
                       zbh, zbl, ebh, ebl, zn2, en2, rbm, cbm);
    hipLaunchKernelGGL(k_rowmax, dim3(256), dim3(256), 0, stream,
                       rbm, lcnt, lists);
    hipLaunchKernelGGL(k_colrescore, dim3(1024), dim3(256), 0, stream,
                       z, emb, zn2, en2, cbm, wscol);
    hipLaunchKernelGGL(k_rowrescore, dim3(8, 16), dim3(256), 0, stream,
                       z, emb, zn2, en2, lists, lcnt, wsrow);
    hipLaunchKernelGGL(k_tokens, dim3(256), dim3(256), 0, stream,
                       z, emb, wsrow, cnts, lacc, out_zq, out_idx);
    hipLaunchKernelGGL(k_tail, dim3(64), dim3(1024), 0, stream,
                       z, emb, prob, wscol, cnts, lacc,
                       out_newemb, out_loss, out_perp, out_prob);
}

// Round 7
// 402.499 us; speedup vs baseline: 1.3400x; 1.3400x over previous
//
#include <hip/hip_runtime.h>

// VectorQuantiser forward, MI355X fp32.
// N=65536 tokens (16x64x64, channel dim 64 strided by 4096), K=1024 codes, D=64.
//
// Round 9: same MFMA+shortlist+exact-rescore architecture as round 8 (passed,
// bit-identical outputs), with the three pathological kernels fixed:
//  - k_prep z-part: LDS transpose so the bf16 hi/lo stores are lane-contiguous
//    (round-8 wrote 64 lanes at 128B stride = 64 partial sectors per instr;
//    suspected ~200us of the missing time).
//  - k_rowrescore: grid (8,64)=512 blocks, thread-per-candidate in lockstep
//    over the 128 codes (k wave-uniform -> e via s_load). Round-8 used 128
//    blocks: Occupancy 4.5%, VALU 5.8%, 170us for ~25us of work.
//  - k_colrescore: parallel threshold scan + LDS hit list (was a 512-iter
//    serial loop per block).
// All rounding-sensitive fp paths are verbatim from the passing code: the
// 4-chain fmaf dot, np_pairwise64_sq, d-combine, key packing, atomicMax ties.

#define MARGIN 2e-4f

// ---- ws layout (bytes) ----
#define WS_ROW   0         // u64 wsrow[65536]
#define WS_COL   524288    // u64 wscol[1024]
#define WS_CNT   532480    // u32 counts[1024]
#define WS_LOSS  536576    // double loss_acc
#define WS_EN2   536592    // float en2[1024]
#define WS_LCNT  540688    // u32 lcnt[8]
#define WS_ZN2   541696    // float zn2[65536]            (256KB)
#define WS_EBH   803840    // u16 ebf_hi[1024*64]         (128KB)
#define WS_EBL   934912    // u16 ebf_lo[1024*64]         (128KB)
#define WS_RBM   1065984   // f32 rowbm[65536][8]         (2MB)
#define WS_CBM   3163136   // f32 colbm[1024][512]        (2MB)
#define WS_BYTES 5260288
#define WS_ZERO  540720    // memset range: row/col/cnt/loss/lcnt

typedef __attribute__((ext_vector_type(8))) short short8v;
typedef __attribute__((ext_vector_type(4))) float f32x4;

__device__ __forceinline__ unsigned int f32_ord(float x) {
    unsigned int b = __float_as_uint(x);
    return (b & 0x80000000u) ? ~b : (b | 0x80000000u);
}

__device__ __forceinline__ unsigned short f2bf(float f) {  // RNE fp32->bf16
    unsigned int u = __float_as_uint(f);
    return (unsigned short)((u + 0x7FFFu + ((u >> 16) & 1u)) >> 16);
}
__device__ __forceinline__ float bf2f(unsigned short h) {
    return __uint_as_float((unsigned int)h << 16);
}

// numpy pairwise sum of squares over 64 values (verbatim from passing code).
template <typename F>
__device__ __forceinline__ float np_pairwise64_sq(F get) {
    float r[8];
#pragma unroll
    for (int j = 0; j < 8; ++j) {
        float v = get(j);
        r[j] = __fmul_rn(v, v);
    }
#pragma unroll
    for (int i = 8; i < 64; i += 8) {
#pragma unroll
        for (int j = 0; j < 8; ++j) {
            float v = get(i + j);
            r[j] = __fadd_rn(r[j], __fmul_rn(v, v));
        }
    }
    return __fadd_rn(__fadd_rn(__fadd_rn(r[0], r[1]), __fadd_rn(r[2], r[3])),
                     __fadd_rn(__fadd_rn(r[4], r[5]), __fadd_rn(r[6], r[7])));
}

// ---- K0: norms + bf16 hi/lo splits ----
// blocks 0..1023: 64 tokens each, LDS-transposed so global writes coalesce.
// blocks 1024..1027: e-part (1024 codes, tiny).
__global__ __launch_bounds__(256) void k_prep(
    const float* __restrict__ z, const float* __restrict__ emb,
    float* __restrict__ en2, float* __restrict__ zn2,
    unsigned int* __restrict__ zbh32, unsigned int* __restrict__ zbl32,
    unsigned int* __restrict__ ebh32, unsigned int* __restrict__ ebl32) {
    const int t = threadIdx.x;
    if (blockIdx.x < 1024) {
        const int n0  = blockIdx.x * 64;
        const int b   = n0 >> 12;
        const int hw0 = n0 & 4095;

        __shared__ float        zl[64][65];   // [ch][tok], pad 65
        __shared__ unsigned int oh[64][33];   // [tok][wd], pad 33
        __shared__ unsigned int ol[64][33];

        // load 64 tok x 64 ch, coalesced 256B per wave-instr
#pragma unroll
        for (int it = 0; it < 16; ++it) {
            int idx = it * 256 + t;
            int c = idx >> 6, tok = idx & 63;
            zl[c][tok] = z[(size_t)b * 262144 + (size_t)c * 4096 + hw0 + tok];
        }
        __syncthreads();

        // wave0: exact norms (same values, same chain as zp[i*4096] reads)
        const int tk = t & 63, q = t >> 6;
        if (q == 0)
            zn2[n0 + tk] = np_pairwise64_sq([&](int i) { return zl[i][tk]; });

        // all 4 waves: hi/lo split, 8 words per thread
#pragma unroll
        for (int w8 = 0; w8 < 8; ++w8) {
            int wd = q * 8 + w8;
            float z0 = zl[2 * wd][tk], z1 = zl[2 * wd + 1][tk];
            unsigned short h0 = f2bf(z0), h1 = f2bf(z1);
            oh[tk][wd] = (unsigned int)h0 | ((unsigned int)h1 << 16);
            unsigned short l0 = f2bf(__fsub_rn(z0, bf2f(h0)));
            unsigned short l1 = f2bf(__fsub_rn(z1, bf2f(h1)));
            ol[tk][wd] = (unsigned int)l0 | ((unsigned int)l1 << 16);
        }
        __syncthreads();

        // write out coalesced: lanes cover (tok, wd) with wd fastest
#pragma unroll
        for (int it = 0; it < 8; ++it) {
            int idx = it * 256 + t;
            int tok = idx >> 5, wd = idx & 31;
            zbh32[(size_t)(n0 + tok) * 32 + wd] = oh[tok][wd];
            zbl32[(size_t)(n0 + tok) * 32 + wd] = ol[tok][wd];
        }
    } else {
        const int k = (blockIdx.x - 1024) * 256 + t;
        const float* a = emb + (size_t)k * 64;
        float ar[64];
#pragma unroll
        for (int i = 0; i < 64; ++i) ar[i] = a[i];
        en2[k] = np_pairwise64_sq([&](int i) { return ar[i]; });
#pragma unroll
        for (int wd = 0; wd < 32; ++wd) {
            float e0 = ar[2 * wd], e1 = ar[2 * wd + 1];
            unsigned short h0 = f2bf(e0), h1 = f2bf(e1);
            ebh32[k * 32 + wd] = (unsigned int)h0 | ((unsigned int)h1 << 16);
            unsigned short l0 = f2bf(__fsub_rn(e0, bf2f(h0)));
            unsigned short l1 = f2bf(__fsub_rn(e1, bf2f(h1)));
            ebl32[k * 32 + wd] = (unsigned int)l0 | ((unsigned int)l1 << 16);
        }
    }
}

// ---- K1: approximate scores via 3-pass bf16 MFMA + block maxes ----
// grid 512 blocks x 512 thr (8 waves). Wave w: tokens tw..tw+15, all 1024
// codes in 64 chunks of 16. s~ = fadd(fsub(-zn2, en2), 2*mfma_dot).
__global__ __launch_bounds__(512) void k_mfma(
    const unsigned short* __restrict__ zbh, const unsigned short* __restrict__ zbl,
    const unsigned short* __restrict__ ebh, const unsigned short* __restrict__ ebl,
    const float* __restrict__ zn2, const float* __restrict__ en2,
    float* __restrict__ rbm, float* __restrict__ cbm) {
    const int t = threadIdx.x, l = t & 63, w = t >> 6;
    const int n0 = blockIdx.x * 128;
    const int tw = n0 + w * 16;
    const int lm = l & 15, kg = l >> 4;

    __shared__ float en2l[1024];
    __shared__ float colmax[8][1024];

    for (int i = t; i < 1024; i += 512) en2l[i] = en2[i];
    __syncthreads();

    const int tok = tw + lm;
    const short8v ah0 = *reinterpret_cast<const short8v*>(zbh + tok * 64 + kg * 8);
    const short8v ah1 = *reinterpret_cast<const short8v*>(zbh + tok * 64 + 32 + kg * 8);
    const short8v al0 = *reinterpret_cast<const short8v*>(zbl + tok * 64 + kg * 8);
    const short8v al1 = *reinterpret_cast<const short8v*>(zbl + tok * 64 + 32 + kg * 8);

    float nzn2[4];
    {
        const float4 zv = *reinterpret_cast<const float4*>(zn2 + tw + kg * 4);
        nzn2[0] = -zv.x; nzn2[1] = -zv.y; nzn2[2] = -zv.z; nzn2[3] = -zv.w;
    }

    float rmax[4] = {-3.4e38f, -3.4e38f, -3.4e38f, -3.4e38f};

    for (int c = 0; c < 64; ++c) {
        const int code = c * 16 + lm;
        const unsigned short* eh = ebh + code * 64 + kg * 8;
        const unsigned short* el = ebl + code * 64 + kg * 8;
        const short8v bh0 = *reinterpret_cast<const short8v*>(eh);
        const short8v bh1 = *reinterpret_cast<const short8v*>(eh + 32);
        const short8v bl0 = *reinterpret_cast<const short8v*>(el);
        const short8v bl1 = *reinterpret_cast<const short8v*>(el + 32);

        f32x4 acc = {0.f, 0.f, 0.f, 0.f};
        acc = __builtin_amdgcn_mfma_f32_16x16x32_bf16(ah0, bh0, acc, 0, 0, 0);
        acc = __builtin_amdgcn_mfma_f32_16x16x32_bf16(ah1, bh1, acc, 0, 0, 0);
        acc = __builtin_amdgcn_mfma_f32_16x16x32_bf16(ah0, bl0, acc, 0, 0, 0);
        acc = __builtin_amdgcn_mfma_f32_16x16x32_bf16(ah1, bl1, acc, 0, 0, 0);
        acc = __builtin_amdgcn_mfma_f32_16x16x32_bf16(al0, bh0, acc, 0, 0, 0);
        acc = __builtin_amdgcn_mfma_f32_16x16x32_bf16(al1, bh1, acc, 0, 0, 0);

        const float en2v = en2l[code];
        float cm = -3.4e38f;
#pragma unroll
        for (int j = 0; j < 4; ++j) {
            float s = __fadd_rn(__fsub_rn(nzn2[j], en2v), 2.0f * acc[j]);
            rmax[j] = fmaxf(rmax[j], s);
            cm = fmaxf(cm, s);
        }
        // column: combine the 4 row-quadrants -> wave's 16-token col max
        cm = fmaxf(cm, __shfl_xor(cm, 16, 64));
        cm = fmaxf(cm, __shfl_xor(cm, 32, 64));
        if (l < 16) colmax[w][c * 16 + l] = cm;

        if ((c & 7) == 7) {  // flush a 128-code block of row maxes
#pragma unroll
            for (int j = 0; j < 4; ++j) {
                float r = rmax[j];
                r = fmaxf(r, __shfl_xor(r, 1, 64));
                r = fmaxf(r, __shfl_xor(r, 2, 64));
                r = fmaxf(r, __shfl_xor(r, 4, 64));
                r = fmaxf(r, __shfl_xor(r, 8, 64));
                if (lm == 0)
                    rbm[(size_t)(tw + kg * 4 + j) * 8 + (c >> 3)] = r;
                rmax[j] = -3.4e38f;
            }
        }
    }
    __syncthreads();
    for (int code = t; code < 1024; code += 512) {
        float m = colmax[0][code];
#pragma unroll
        for (int q = 1; q < 8; ++q) m = fmaxf(m, colmax[q][code]);
        cbm[(size_t)code * 512 + blockIdx.x] = m;
    }
}

// ---- K2: per-token candidate lists from row block-maxes ----
__global__ __launch_bounds__(256) void k_rowmax(
    const float* __restrict__ rbm, unsigned int* __restrict__ lcnt,
    unsigned int* __restrict__ lists) {
    const int n = blockIdx.x * 256 + threadIdx.x;
    const float* bm = rbm + (size_t)n * 8;
    float v[8];
    float g = -3.4e38f;
#pragma unroll
    for (int i = 0; i < 8; ++i) { v[i] = bm[i]; g = fmaxf(g, v[i]); }
    const float thr = g - MARGIN;
#pragma unroll
    for (int cb = 0; cb < 8; ++cb) {
        if (v[cb] >= thr) {
            unsigned int pos = atomicAdd(&lcnt[cb], 1u);
            lists[cb * 65536 + pos] = (unsigned int)n;
        }
    }
}

// ---- K3: exact row rescore (bit-identical 4-chain d) over candidates ----
// grid (8 code-blocks, 64), 256 thr: thread-per-candidate, lockstep kk loop
// (k wave-uniform -> e stays on the s_load path). List entries are near-
// sorted token runs -> z loads stay roughly coalesced.
__global__ __launch_bounds__(256) void k_rowrescore(
    const float* __restrict__ z, const float* __restrict__ emb,
    const float* __restrict__ zn2, const float* __restrict__ en2,
    const unsigned int* __restrict__ lists, const unsigned int* __restrict__ lcnt,
    unsigned long long* __restrict__ wsrow) {
    const int cb = blockIdx.x;
    const unsigned int cnt = lcnt[cb];
    const unsigned int* list = lists + cb * 65536;
    const float4* E4 = reinterpret_cast<const float4*>(emb);
    for (unsigned int i = blockIdx.y * 256 + threadIdx.x; i < cnt;
         i += 64 * 256) {
        const int n = (int)list[i];
        const int b = n >> 12, hw = n & 4095;
        const float* zp = z + (size_t)b * 262144 + hw;
        const float nzn2 = -zn2[n];
        unsigned long long best = 0ull;
        for (int kk = 0; kk < 128; ++kk) {
            const int k = cb * 128 + kk;
            const float4* ek = E4 + (size_t)k * 16;  // wave-uniform -> s_load
            float c0 = 0.f, c1 = 0.f, c2 = 0.f, c3 = 0.f;
#pragma unroll
            for (int j = 0; j < 16; ++j) {
                float4 e = ek[j];
                c0 = fmaf(e.x, zp[(size_t)(4 * j + 0) * 4096], c0);
                c1 = fmaf(e.y, zp[(size_t)(4 * j + 1) * 4096], c1);
                c2 = fmaf(e.z, zp[(size_t)(4 * j + 2) * 4096], c2);
                c3 = fmaf(e.w, zp[(size_t)(4 * j + 3) * 4096], c3);
            }
            float dot = (c0 + c1) + (c2 + c3);
            float d = __fadd_rn(__fsub_rn(nzn2, en2[k]), 2.0f * dot);
            unsigned long long key =
                ((unsigned long long)f32_ord(d) << 32) |
                (unsigned long long)(unsigned int)(~(unsigned int)k);
            if (key > best) best = key;   // ties: larger key = smaller k
        }
        atomicMax(&wsrow[n], best);
    }
}

// ---- K4: exact column rescore over candidate token-groups ----
// block per code: parallel threshold scan -> LDS hit list -> rescore hits.
__global__ __launch_bounds__(256) void k_colrescore(
    const float* __restrict__ z, const float* __restrict__ emb,
    const float* __restrict__ zn2, const float* __restrict__ en2,
    const float* __restrict__ cbm, unsigned long long* __restrict__ wscol) {
    const int k = blockIdx.x, t = threadIdx.x;
    __shared__ float red[256];
    __shared__ int   hlist[512];
    __shared__ int   hcnt;
    float a  = cbm[(size_t)k * 512 + t];
    float b2 = cbm[(size_t)k * 512 + 256 + t];
    red[t] = fmaxf(a, b2);
    if (t == 0) hcnt = 0;
    __syncthreads();
    for (int st = 128; st; st >>= 1) {
        if (t < st) red[t] = fmaxf(red[t], red[t + st]);
        __syncthreads();
    }
    const float thr = red[0] - MARGIN;
    if (a >= thr)  { int p = atomicAdd(&hcnt, 1); hlist[p] = t; }
    if (b2 >= thr) { int p = atomicAdd(&hcnt, 1); hlist[p] = t + 256; }
    __syncthreads();
    const int hc = hcnt;
    const float en2k = en2[k];
    const float4* ek = reinterpret_cast<const float4*>(emb + (size_t)k * 64);

    for (int h = 0; h < hc; ++h) {
        const int g = hlist[h];
        if (t < 128) {
            const int n = g * 128 + t;
            const int b = n >> 12, hw = n & 4095;
            const float* zp = z + (size_t)b * 262144 + hw;
            float c0 = 0.f, c1 = 0.f, c2 = 0.f, c3 = 0.f;
#pragma unroll
            for (int j = 0; j < 16; ++j) {
                float4 e = ek[j];
                c0 = fmaf(e.x, zp[(size_t)(4 * j + 0) * 4096], c0);
                c1 = fmaf(e.y, zp[(size_t)(4 * j + 1) * 4096], c1);
                c2 = fmaf(e.z, zp[(size_t)(4 * j + 2) * 4096], c2);
                c3 = fmaf(e.w, zp[(size_t)(4 * j + 3) * 4096], c3);
            }
            float dot = (c0 + c1) + (c2 + c3);
            float d = __fadd_rn(__fsub_rn(-zn2[n], en2k), 2.0f * dot);
            unsigned long long key =
                ((unsigned long long)f32_ord(d) << 32) |
                (unsigned long long)(unsigned int)(~(unsigned int)n);
#pragma unroll
            for (int m = 1; m < 64; m <<= 1) {
                unsigned long long o = __shfl_xor(key, m, 64);
                if (o > key) key = o;    // ties: larger key = smaller n
            }
            if ((t & 63) == 0) atomicMax(&wscol[k], key);
        }
    }
}

// ---- K5: per-token outputs: z_q (straight-through), indices, hist, loss ----
__global__ __launch_bounds__(256) void k_tokens(
    const float* __restrict__ z, const float* __restrict__ emb,
    const unsigned long long* __restrict__ wsrow,
    unsigned int* __restrict__ counts, double* __restrict__ loss_acc,
    float* __restrict__ out_zq, float* __restrict__ out_idx) {
    const int n  = blockIdx.x * 256 + threadIdx.x;
    const int b  = n >> 12;
    const int hw = n & 4095;

    unsigned long long key = wsrow[n];
    int idx = (int)(~(unsigned int)(key & 0xFFFFFFFFull));
    out_idx[n] = (float)idx;
    atomicAdd(&counts[idx], 1u);

    const float* zp = z + (size_t)b * 262144 + hw;
    float*       op = out_zq + (size_t)b * 262144 + hw;
    const float* ep = emb + (size_t)idx * 64;

    double ls = 0.0;
#pragma unroll
    for (int c = 0; c < 64; ++c) {
        float zc   = zp[(size_t)c * 4096];
        float eq   = ep[c];
        float diff = __fsub_rn(eq, zc);              // fl(z_q - zc)
        float sq   = __fmul_rn(diff, diff);
        ls += (double)sq;
        op[(size_t)c * 4096] = __fadd_rn(zc, diff);  // zc + fl(z_q - zc)
    }

    __shared__ double sred[256];
    sred[threadIdx.x] = ls;
    __syncthreads();
    for (int st = 128; st; st >>= 1) {
        if (threadIdx.x < st) sred[threadIdx.x] += sred[threadIdx.x + st];
        __syncthreads();
    }
    if (threadIdx.x == 0) atomicAdd(loss_acc, sred[0]);
}

// ---- K6: tail — new embedding (all blocks) + scalars (block 0 only) ----
__global__ __launch_bounds__(1024) void k_tail(
    const float* __restrict__ z, const float* __restrict__ emb,
    const float* __restrict__ embed_prob,
    const unsigned long long* __restrict__ wscol,
    const unsigned int* __restrict__ counts,
    const double* __restrict__ loss_acc,
    float* __restrict__ out_newemb, float* __restrict__ out_loss,
    float* __restrict__ out_perp, float* __restrict__ out_prob) {
    const int k = blockIdx.x * 16 + (threadIdx.x >> 6);
    const int c = threadIdx.x & 63;

    float avg  = (float)counts[k] * (1.0f / 65536.0f);
    float pnew = __fadd_rn(__fmul_rn(embed_prob[k], 0.99f),
                           __fmul_rn(0.01f, avg));
    float tt = __fdiv_rn(__fmul_rn(__fmul_rn(pnew, 1024.0f), 10.0f), 0.01f);
    float dk = expf(__fsub_rn(-tt, 1e-3f));
    float omd = __fsub_rn(1.0f, dk);

    unsigned long long ck = wscol[k];
    int cn  = (int)(~(unsigned int)(ck & 0xFFFFFFFFull));
    int cb  = cn >> 12;
    int chw = cn & 4095;

    float rf = z[(size_t)cb * 262144 + (size_t)c * 4096 + chw];
    float e  = emb[(size_t)k * 64 + c];
    out_newemb[(size_t)k * 64 + c] =
        __fadd_rn(__fmul_rn(e, omd), __fmul_rn(rf, dk));

    if (blockIdx.x == 0) {
        const int q = threadIdx.x;

        float avg2  = (float)counts[q] * (1.0f / 65536.0f);
        float pnew2 = __fadd_rn(__fmul_rn(embed_prob[q], 0.99f),
                                __fmul_rn(0.01f, avg2));
        out_prob[q] = pnew2;

        float term = __fmul_rn(avg2, logf(__fadd_rn(avg2, 1e-10f)));
        __shared__ double red[1024];
        red[q] = (double)term;
        __syncthreads();
        for (int st = 512; st; st >>= 1) {
            if (q < st) red[q] += red[q + st];
            __syncthreads();
        }
        if (q == 0) {
            float s32 = (float)red[0];
            out_perp[0] = expf(-s32);
            double lm = loss_acc[0] / 4194304.0;
            float  m  = (float)lm;
            out_loss[0] = __fadd_rn(__fmul_rn(0.25f, m), m);  // BETA*m + m
        }
    }
}

extern "C" void kernel_launch(void* const* d_in, const int* in_sizes, int n_in,
                              void* d_out, int out_size, void* d_ws, size_t ws_size,
                              hipStream_t stream) {
    const float* z    = (const float*)d_in[0];   // 16*64*64*64
    const float* emb  = (const float*)d_in[1];   // 1024*64
    const float* prob = (const float*)d_in[2];   // 1024

    float* out        = (float*)d_out;
    float* out_zq     = out;                 // 4194304 floats (16.777 MB)
    float* out_loss   = out + 4194304;
    float* out_perp   = out + 4194305;
    float* out_newemb = out + 4194306;
    float* out_prob   = out + 4259842;
    float* out_idx    = out + 4260866;

    char* ws = (char*)d_ws;
    unsigned long long* wsrow = (unsigned long long*)(ws + WS_ROW);
    unsigned long long* wscol = (unsigned long long*)(ws + WS_COL);
    unsigned int*       cnts  = (unsigned int*)(ws + WS_CNT);
    double*             lacc  = (double*)(ws + WS_LOSS);
    float*              en2   = (float*)(ws + WS_EN2);
    unsigned int*       lcnt  = (unsigned int*)(ws + WS_LCNT);
    float*              zn2   = (float*)(ws + WS_ZN2);
    unsigned short*     ebh   = (unsigned short*)(ws + WS_EBH);
    unsigned short*     ebl   = (unsigned short*)(ws + WS_EBL);
    float*              rbm   = (float*)(ws + WS_RBM);
    float*              cbm   = (float*)(ws + WS_CBM);

    // out_zq doubles as scratch before k_tokens rewrites it:
    //   zbf_hi u16[4.2M] @ bytes [0, 8388608)
    //   zbf_lo u16[4.2M] @ bytes [8388608, 16777216)
    //   lists  u32[8][65536] @ bytes [0, 2097152)   (after k_mfma is done)
    unsigned short* zbh  = (unsigned short*)out_zq;
    unsigned short* zbl  = (unsigned short*)((char*)out_zq + 8388608);
    unsigned int*  lists = (unsigned int*)out_zq;

    hipMemsetAsync(d_ws, 0, WS_ZERO, stream);

    hipLaunchKernelGGL(k_prep, dim3(1028), dim3(256), 0, stream,
                       z, emb, en2, zn2,
                       (unsigned int*)zbh, (unsigned int*)zbl,
                       (unsigned int*)ebh, (unsigned int*)ebl);
    hipLaunchKernelGGL(k_mfma, dim3(512), dim3(512), 0, stream,
                       zbh, zbl, ebh, ebl, zn2, en2, rbm, cbm);
    hipLaunchKernelGGL(k_rowmax, dim3(256), dim3(256), 0, stream,
                       rbm, lcnt, lists);
    hipLaunchKernelGGL(k_colrescore, dim3(1024), dim3(256), 0, stream,
                       z, emb, zn2, en2, cbm, wscol);
    hipLaunchKernelGGL(k_rowrescore, dim3(8, 64), dim3(256), 0, stream,
                       z, emb, zn2, en2, lists, lcnt, wsrow);
    hipLaunchKernelGGL(k_tokens, dim3(256), dim3(256), 0, stream,
                       z, emb, wsrow, cnts, lacc, out_zq, out_idx);
    hipLaunchKernelGGL(k_tail, dim3(64), dim3(1024), 0, stream,
                       z, emb, prob, wscol, cnts, lacc,
                       out_newemb, out_loss, out_perp, out_prob);
}